// Round 3
// baseline (217.733 us; speedup 1.0000x reference)
//
#include <hip/hip_runtime.h>
#include <hip/hip_bf16.h>
#include <math.h>

#define N_NODES 40000
#define N_EDGES 640000
#define D 128
#define LN_EPS 1e-5f
#define SCAN_B 512
#define SCAN_NB ((N_NODES + SCAN_B - 1) / SCAN_B)   // 79

__device__ __forceinline__ float f4get(const float4& v, int j) {
    return j == 0 ? v.x : j == 1 ? v.y : j == 2 ? v.z : v.w;
}

// ---------------------------------------------------------------------------
// GEMM: hpack[node][feat] = float2( x@Wm+bm , exp(x@Wv+bv) )
// block 256 threads, BM=64 nodes, BN=128 (full), K staged in chunks of 16
// ---------------------------------------------------------------------------
__global__ __launch_bounds__(256) void gemm_kernel(
    const float* __restrict__ x, const float* __restrict__ Wm,
    const float* __restrict__ bm, const float* __restrict__ Wv,
    const float* __restrict__ bv, float2* __restrict__ hpack)
{
    __shared__ float xs[64][24];
    __shared__ float wms[16][128];
    __shared__ float wvs[16][128];

    const int t = threadIdx.x;
    const int nbase = blockIdx.x * 64;
    const int tx = t & 31;
    const int ty = t >> 5;

    float accm[8][4] = {};
    float accv[8][4] = {};

    for (int k0 = 0; k0 < D; k0 += 16) {
        if (k0) __syncthreads();
        {
            int row = t >> 2, c4 = (t & 3) << 2;
            float4 v = *(const float4*)&x[(size_t)(nbase + row) * D + k0 + c4];
            xs[row][c4 + 0] = v.x; xs[row][c4 + 1] = v.y;
            xs[row][c4 + 2] = v.z; xs[row][c4 + 3] = v.w;
        }
        #pragma unroll
        for (int j = 0; j < 2; ++j) {
            int f4 = t + 256 * j;
            int row = f4 >> 5, c4 = (f4 & 31) << 2;
            *(float4*)&wms[row][c4] = *(const float4*)&Wm[(size_t)(k0 + row) * D + c4];
            *(float4*)&wvs[row][c4] = *(const float4*)&Wv[(size_t)(k0 + row) * D + c4];
        }
        __syncthreads();

        #pragma unroll
        for (int kk4 = 0; kk4 < 4; ++kk4) {
            float4 xr[8];
            #pragma unroll
            for (int r = 0; r < 8; ++r)
                xr[r] = *(float4*)&xs[ty * 8 + r][kk4 * 4];
            #pragma unroll
            for (int j = 0; j < 4; ++j) {
                float4 wm4 = *(float4*)&wms[kk4 * 4 + j][tx * 4];
                float4 wv4 = *(float4*)&wvs[kk4 * 4 + j][tx * 4];
                #pragma unroll
                for (int r = 0; r < 8; ++r) {
                    float xv = f4get(xr[r], j);
                    accm[r][0] = fmaf(xv, wm4.x, accm[r][0]);
                    accm[r][1] = fmaf(xv, wm4.y, accm[r][1]);
                    accm[r][2] = fmaf(xv, wm4.z, accm[r][2]);
                    accm[r][3] = fmaf(xv, wm4.w, accm[r][3]);
                    accv[r][0] = fmaf(xv, wv4.x, accv[r][0]);
                    accv[r][1] = fmaf(xv, wv4.y, accv[r][1]);
                    accv[r][2] = fmaf(xv, wv4.z, accv[r][2]);
                    accv[r][3] = fmaf(xv, wv4.w, accv[r][3]);
                }
            }
        }
    }

    float4 bm4 = *(const float4*)&bm[tx * 4];
    float4 bv4 = *(const float4*)&bv[tx * 4];
    #pragma unroll
    for (int r = 0; r < 8; ++r) {
        size_t node = nbase + ty * 8 + r;
        float m0 = accm[r][0] + bm4.x, m1 = accm[r][1] + bm4.y;
        float m2 = accm[r][2] + bm4.z, m3 = accm[r][3] + bm4.w;
        float v0 = expf(accv[r][0] + bv4.x), v1 = expf(accv[r][1] + bv4.y);
        float v2 = expf(accv[r][2] + bv4.z), v3 = expf(accv[r][3] + bv4.w);
        float4* dst = (float4*)&hpack[node * D + tx * 4];
        dst[0] = make_float4(m0, v0, m1, v1);
        dst[1] = make_float4(m2, v2, m3, v3);
    }
}

// ---------------------------------------------------------------------------
__global__ void hist_kernel(const int* __restrict__ row, int* __restrict__ counts)
{
    int e = blockIdx.x * blockDim.x + threadIdx.x;
    if (e < N_EDGES) atomicAdd(&counts[row[e]], 1);
}

// ---------------------------------------------------------------------------
__global__ __launch_bounds__(SCAN_B) void scan_partial_kernel(
    const int* __restrict__ counts, int* __restrict__ partials)
{
    int idx = blockIdx.x * SCAN_B + threadIdx.x;
    int c = (idx < N_NODES) ? counts[idx] : 0;
    int lane = threadIdx.x & 63, wid = threadIdx.x >> 6;
    #pragma unroll
    for (int off = 32; off >= 1; off >>= 1) c += __shfl_xor(c, off);
    __shared__ int ws[SCAN_B / 64];
    if (lane == 0) ws[wid] = c;
    __syncthreads();
    if (threadIdx.x == 0) {
        int s = 0;
        #pragma unroll
        for (int i = 0; i < SCAN_B / 64; ++i) s += ws[i];
        partials[blockIdx.x] = s;
    }
}

// ---------------------------------------------------------------------------
__global__ __launch_bounds__(128) void scan_top_kernel(
    const int* __restrict__ partials, int* __restrict__ blockoff)
{
    __shared__ int tmp[128];
    int t = threadIdx.x;
    tmp[t] = (t < SCAN_NB) ? partials[t] : 0;
    __syncthreads();
    for (int off = 1; off < 128; off <<= 1) {
        int v = tmp[t];
        int a = (t >= off) ? tmp[t - off] : 0;
        __syncthreads();
        tmp[t] = v + a;
        __syncthreads();
    }
    if (t < SCAN_NB) blockoff[t] = (t > 0) ? tmp[t - 1] : 0;
}

// ---------------------------------------------------------------------------
__global__ __launch_bounds__(SCAN_B) void scan_write_kernel(
    const int* __restrict__ counts, const int* __restrict__ blockoff,
    int* __restrict__ rowstart, int* __restrict__ cursor)
{
    int idx = blockIdx.x * SCAN_B + threadIdx.x;
    int c = (idx < N_NODES) ? counts[idx] : 0;
    int lane = threadIdx.x & 63, wid = threadIdx.x >> 6;

    int inc = c;
    #pragma unroll
    for (int off = 1; off < 64; off <<= 1) {
        int u = __shfl_up(inc, off);
        if (lane >= off) inc += u;
    }
    __shared__ int ws[SCAN_B / 64];
    if (lane == 63) ws[wid] = inc;
    __syncthreads();
    if (threadIdx.x == 0) {
        int run = 0;
        #pragma unroll
        for (int i = 0; i < SCAN_B / 64; ++i) { int v = ws[i]; ws[i] = run; run += v; }
    }
    __syncthreads();
    int excl = inc - c + ws[wid] + blockoff[blockIdx.x];
    if (idx < N_NODES) {
        rowstart[idx] = excl;
        cursor[idx]   = excl;
        if (idx == N_NODES - 1) rowstart[N_NODES] = excl + c;
    }
}

// ---------------------------------------------------------------------------
// Scatter edges into CSR order, packed: epack[pos] = {colbits, wm, wv, 0}
// ---------------------------------------------------------------------------
__global__ void scatter_kernel(
    const int* __restrict__ row, const int* __restrict__ col,
    const float* __restrict__ ewm, const float* __restrict__ ewv,
    int* __restrict__ cursor, float4* __restrict__ epack)
{
    int e = blockIdx.x * blockDim.x + threadIdx.x;
    if (e >= N_EDGES) return;
    int r = row[e];
    int pos = atomicAdd(&cursor[r], 1);
    epack[pos] = make_float4(__int_as_float(col[e]), ewm[e], ewv[e], 0.0f);
}

// ---------------------------------------------------------------------------
// Per-node aggregation + degree normalization + LayerNorm, fused.
// 4-wide edge unroll for MLP; one float2 gather per thread per edge.
// ---------------------------------------------------------------------------
__global__ __launch_bounds__(128) void agg_kernel(
    const float2* __restrict__ hpack, const int* __restrict__ rowstart,
    const float4* __restrict__ epack,
    const float* __restrict__ gamma, const float* __restrict__ beta,
    float* __restrict__ out)
{
    const int n = blockIdx.x;
    const int d = threadIdx.x;
    const int start = rowstart[n];
    const int end = rowstart[n + 1];

    float am = 0.f, av = 0.f;
    int e = start;
    const int nquad = (end - start) >> 2;

    for (int q = 0; q < nquad; ++q, e += 4) {
        float4 m0 = epack[e + 0];
        float4 m1 = epack[e + 1];
        float4 m2 = epack[e + 2];
        float4 m3 = epack[e + 3];
        int c0 = __float_as_int(m0.x), c1 = __float_as_int(m1.x);
        int c2 = __float_as_int(m2.x), c3 = __float_as_int(m3.x);
        float2 h0 = hpack[(size_t)c0 * D + d];
        float2 h1 = hpack[(size_t)c1 * D + d];
        float2 h2 = hpack[(size_t)c2 * D + d];
        float2 h3 = hpack[(size_t)c3 * D + d];
        am = fmaf(h0.x, m0.y, am);
        av = fmaf(m0.y * m0.y, h0.y, fmaf(h0.x * h0.x, m0.z, av));
        am = fmaf(h1.x, m1.y, am);
        av = fmaf(m1.y * m1.y, h1.y, fmaf(h1.x * h1.x, m1.z, av));
        am = fmaf(h2.x, m2.y, am);
        av = fmaf(m2.y * m2.y, h2.y, fmaf(h2.x * h2.x, m2.z, av));
        am = fmaf(h3.x, m3.y, am);
        av = fmaf(m3.y * m3.y, h3.y, fmaf(h3.x * h3.x, m3.z, av));
    }
    for (; e < end; ++e) {
        float4 m0 = epack[e];
        int c0 = __float_as_int(m0.x);
        float2 h0 = hpack[(size_t)c0 * D + d];
        am = fmaf(h0.x, m0.y, am);
        av = fmaf(m0.y * m0.y, h0.y, fmaf(h0.x * h0.x, m0.z, av));
    }

    float degi = 1.0f / fmaxf((float)(end - start), 1.0f);
    am *= degi;
    av *= degi * degi;

    __shared__ float red[2];
    const int lane = d & 63, wid = d >> 6;

    float s = am;
    #pragma unroll
    for (int off = 32; off >= 1; off >>= 1) s += __shfl_xor(s, off);
    if (lane == 0) red[wid] = s;
    __syncthreads();
    float mu = (red[0] + red[1]) * (1.0f / 128.0f);
    float diff = am - mu;
    __syncthreads();

    float q2 = diff * diff;
    #pragma unroll
    for (int off = 32; off >= 1; off >>= 1) q2 += __shfl_xor(q2, off);
    if (lane == 0) red[wid] = q2;
    __syncthreads();
    float var = (red[0] + red[1]) * (1.0f / 128.0f);

    float o = diff * rsqrtf(var + LN_EPS) * gamma[d] + beta[d];
    out[(size_t)n * D + d] = o;
    out[(size_t)N_NODES * D + (size_t)n * D + d] = av;
}

// ---------------------------------------------------------------------------
extern "C" void kernel_launch(void* const* d_in, const int* in_sizes, int n_in,
                              void* d_out, int out_size, void* d_ws, size_t ws_size,
                              hipStream_t stream)
{
    const float* x     = (const float*)d_in[0];
    const int*   eidx  = (const int*)d_in[1];
    const float* ewm   = (const float*)d_in[2];
    const float* ewv   = (const float*)d_in[3];
    const float* Wm    = (const float*)d_in[4];
    const float* bm    = (const float*)d_in[5];
    const float* Wv    = (const float*)d_in[6];
    const float* bv    = (const float*)d_in[7];
    const float* gamma = (const float*)d_in[8];
    const float* beta  = (const float*)d_in[9];
    const int* row = eidx;
    const int* col = eidx + N_EDGES;

    char* ws = (char*)d_ws;
    size_t off = 0;
    auto alloc = [&](size_t bytes) {
        void* p = ws + off;
        off += (bytes + 255) & ~(size_t)255;
        return p;
    };
    float2* hpack  = (float2*)alloc((size_t)N_NODES * D * 8);
    int*   counts  = (int*)alloc((size_t)N_NODES * 4);
    int*   rowstart= (int*)alloc((size_t)(N_NODES + 1) * 4);
    int*   cursor  = (int*)alloc((size_t)N_NODES * 4);
    float4* epack  = (float4*)alloc((size_t)N_EDGES * 16);
    int*   partials= (int*)alloc((size_t)SCAN_NB * 4);
    int*   blockoff= (int*)alloc((size_t)SCAN_NB * 4);

    hipMemsetAsync(counts, 0, (size_t)N_NODES * 4, stream);

    gemm_kernel<<<N_NODES / 64, 256, 0, stream>>>(x, Wm, bm, Wv, bv, hpack);
    hist_kernel<<<(N_EDGES + 255) / 256, 256, 0, stream>>>(row, counts);
    scan_partial_kernel<<<SCAN_NB, SCAN_B, 0, stream>>>(counts, partials);
    scan_top_kernel<<<1, 128, 0, stream>>>(partials, blockoff);
    scan_write_kernel<<<SCAN_NB, SCAN_B, 0, stream>>>(counts, blockoff, rowstart, cursor);
    scatter_kernel<<<(N_EDGES + 255) / 256, 256, 0, stream>>>(
        row, col, ewm, ewv, cursor, epack);
    agg_kernel<<<N_NODES, 128, 0, stream>>>(
        hpack, rowstart, epack, gamma, beta, (float*)d_out);
}